// Round 9
// baseline (490.870 us; speedup 1.0000x reference)
//
#include <hip/hip_runtime.h>

// Problem constants (shapes fixed by reference; N/E derived from in_sizes)
#define NHID 128
#define HDIM 64
#define EPB 8192            // edges per block for bucket scatter
#define MAXBKT 1024         // pow2 pad of NBKT=782 for scans
#define CAP 6144            // LDS sort capacity in bucket_build (>> max bucket size)

typedef __attribute__((ext_vector_type(8))) short bf16x8;
typedef __attribute__((ext_vector_type(4))) float f32x4;

__device__ __forceinline__ unsigned short f2bf_rn(float f) {
    union { float f; unsigned u; } c; c.f = f;
    unsigned r = c.u + 0x7fffu + ((c.u >> 16) & 1u);   // round-to-nearest-even
    return (unsigned short)(r >> 16);
}
__device__ __forceinline__ float bf_lo(unsigned d) {   // low bf16 of dword
    union { unsigned u; float f; } c; c.u = d << 16; return c.f;
}
__device__ __forceinline__ float bf_hi(unsigned d) {   // high bf16 of dword
    union { unsigned u; float f; } c; c.u = d & 0xFFFF0000u; return c.f;
}

// ---------------------------------------------------------------------------
// Kernel 1: fused per-block edge histogram + x->bf16 prep.
// Blocks [0,EB): LDS histogram of the block's 8192 edges -> hmat[block][1024]
// (plain coalesced writes -- no global atomics, no memset needed).
// Blocks [EB,..): convert x fp32 -> xh bf16, 8 elems/thread.
// ---------------------------------------------------------------------------
__global__ __launch_bounds__(256) void hist_prep(
    const int* __restrict__ dst, int* __restrict__ hmat,
    const float* __restrict__ x, unsigned short* __restrict__ xh,
    int E, int EB, long long total8)
{
    if ((int)blockIdx.x < EB) {
        __shared__ int h[MAXBKT];
        int t = threadIdx.x;
        for (int i = t; i < MAXBKT; i += 256) h[i] = 0;
        __syncthreads();
        long long base = (long long)blockIdx.x * EPB;
        for (int p = 0; p < EPB / 256; ++p) {
            long long e = base + p * 256 + t;
            if (e < E) atomicAdd(&h[((unsigned)dst[e]) >> 8], 1);
        }
        __syncthreads();
        int* outp = hmat + (size_t)blockIdx.x * MAXBKT;
        for (int i = t; i < MAXBKT; i += 256) outp[i] = h[i];
    } else {
        long long t8 = (long long)((int)blockIdx.x - EB) * 256 + threadIdx.x;
        if (t8 >= total8) return;
        const float4 a = *(const float4*)(x + t8 * 8);
        const float4 b = *(const float4*)(x + t8 * 8 + 4);
        ushort4 p, q;
        p.x = f2bf_rn(a.x); p.y = f2bf_rn(a.y); p.z = f2bf_rn(a.z); p.w = f2bf_rn(a.w);
        q.x = f2bf_rn(b.x); q.y = f2bf_rn(b.y); q.z = f2bf_rn(b.z); q.w = f2bf_rn(b.w);
        *(ushort4*)(xh + t8 * 8) = p;
        *(ushort4*)(xh + t8 * 8 + 4) = q;
    }
}

// ---------------------------------------------------------------------------
// Kernel 2: per-bucket exclusive scan over blocks. Block j handles bucket j:
// hmat[b][j] (count) -> hmat[b][j] (local start of block b's run in bucket j);
// btot[j] = bucket total. EB=391 <= 512; 2 elements/thread Hillis-Steele.
// ---------------------------------------------------------------------------
__global__ __launch_bounds__(256) void scan_blocks(int* __restrict__ hmat,
                                                   int* __restrict__ btot,
                                                   int EB) {
    __shared__ int sc[512];
    int j = blockIdx.x;                 // bucket
    int t = threadIdx.x;
    int i1 = t, i2 = t + 256;
    int o1 = (i1 < EB) ? hmat[(size_t)i1 * MAXBKT + j] : 0;
    int o2 = (i2 < EB) ? hmat[(size_t)i2 * MAXBKT + j] : 0;
    sc[i1] = o1; sc[i2] = o2;
    __syncthreads();
    for (int off = 1; off < 512; off <<= 1) {
        int v1 = (i1 >= off) ? sc[i1 - off] : 0;
        int v2 = (i2 >= off) ? sc[i2 - off] : 0;
        __syncthreads();
        sc[i1] += v1; sc[i2] += v2;
        __syncthreads();
    }
    if (i1 < EB) hmat[(size_t)i1 * MAXBKT + j] = sc[i1] - o1;   // exclusive
    if (i2 < EB) hmat[(size_t)i2 * MAXBKT + j] = sc[i2] - o2;
    if (t == 0) btot[j] = sc[511];
}

// ---------------------------------------------------------------------------
// Kernel 3: one-block exclusive scan of bucket totals -> bbase (packed starts).
// ---------------------------------------------------------------------------
__global__ __launch_bounds__(1024) void scan_bbase(const int* __restrict__ btot,
                                                   int* __restrict__ bbase, int NBKT) {
    __shared__ int sc[1024];
    int t = threadIdx.x;
    int v = (t < NBKT) ? btot[t] : 0;
    sc[t] = v;
    __syncthreads();
    for (int off = 1; off < 1024; off <<= 1) {
        int u = (t >= off) ? sc[t - off] : 0;
        __syncthreads();
        sc[t] += u;
        __syncthreads();
    }
    bbase[t] = sc[t] - v;               // exclusive
}

// ---------------------------------------------------------------------------
// Kernel 4: deterministic write-coalesced scatter. NO global atomics.
// Re-histogram in LDS, 1024-wide scan (4/thread), LDS staging sort, then
// linear write-out: gpos = (bbase[b] + lstart[block][b]) + rank_in_block.
// Packed global layout (no CAP padding).
// ---------------------------------------------------------------------------
__global__ __launch_bounds__(256) void scatter_det(
    const int* __restrict__ src, const int* __restrict__ dst,
    const int* __restrict__ hmat, const int* __restrict__ bbase,
    unsigned int* __restrict__ bpack, int E, int NBKT)
{
    __shared__ int h[MAXBKT];          // counts -> then gbase
    __shared__ int lofs[MAXBKT];       // inclusive scan of counts
    __shared__ int lcur[MAXBKT];       // staging scatter cursor
    __shared__ unsigned sbuf[EPB];     // block's edges sorted by bucket
    int t = threadIdx.x;
    long long base = (long long)blockIdx.x * EPB;
    int rem = (int)(E - base);
    int nev = rem < EPB ? rem : EPB;

    for (int i = t; i < MAXBKT; i += 256) h[i] = 0;
    __syncthreads();
    for (int p = 0; p < EPB / 256; ++p) {
        int e = p * 256 + t;
        if (e < nev) atomicAdd(&h[((unsigned)dst[base + e]) >> 8], 1);
    }
    __syncthreads();
    #pragma unroll
    for (int j2 = 0; j2 < 4; ++j2) lofs[t + j2 * 256] = h[t + j2 * 256];
    __syncthreads();
    for (int off = 1; off < MAXBKT; off <<= 1) {
        int i0 = t, i1 = t + 256, i2 = t + 512, i3 = t + 768;
        int v0 = lofs[i0] + (i0 >= off ? lofs[i0 - off] : 0);
        int v1 = lofs[i1] + (i1 >= off ? lofs[i1 - off] : 0);
        int v2 = lofs[i2] + (i2 >= off ? lofs[i2 - off] : 0);
        int v3 = lofs[i3] + (i3 >= off ? lofs[i3 - off] : 0);
        __syncthreads();
        lofs[i0] = v0; lofs[i1] = v1; lofs[i2] = v2; lofs[i3] = v3;
        __syncthreads();
    }
    const int* lst = hmat + (size_t)blockIdx.x * MAXBKT;
    for (int i = t; i < MAXBKT; i += 256) {
        int c = h[i];
        lcur[i] = lofs[i] - c;                  // local exclusive prefix
        h[i] = bbase[i] + lst[i];               // gbase (count no longer needed)
    }
    __syncthreads();
    for (int p = 0; p < EPB / 256; ++p) {
        int e = p * 256 + t;
        if (e < nev) {
            int d = dst[base + e];
            int s = src[base + e];
            int b = ((unsigned)d) >> 8;
            int pos = atomicAdd(&lcur[b], 1);   // LDS atomic only
            sbuf[pos] = (((unsigned)d & 255u) << 24) | (unsigned)s;
        }
    }
    __syncthreads();
    for (int p = 0; p < EPB / 256; ++p) {
        int j = p * 256 + t;
        if (j < nev) {
            int lo = 0, hi = NBKT - 1;          // smallest b with lofs[b] > j
            while (lo < hi) {
                int mid = (lo + hi) >> 1;
                if (lofs[mid] > j) hi = mid; else lo = mid + 1;
            }
            int b = lo;
            int prev = b ? lofs[b - 1] : 0;
            bpack[h[b] + (j - prev)] = sbuf[j]; // exact, coalesced runs
        }
    }
}

// ---------------------------------------------------------------------------
// Kernel 5: one block per bucket. LDS-cached in-place sort by local node.
// Packed buckets: beg = bbase[b], m = btot[b].
// ---------------------------------------------------------------------------
__global__ __launch_bounds__(256) void bucket_build(unsigned int* __restrict__ bpack,
                                                    const int* __restrict__ bbase,
                                                    const int* __restrict__ btot,
                                                    int* __restrict__ cnt,
                                                    int* __restrict__ rowptr,
                                                    int N) {
    __shared__ unsigned ebuf[CAP];
    __shared__ int lc[256];
    __shared__ int sc[256];
    int b = blockIdx.x, t = threadIdx.x;
    int beg = bbase[b];
    int m = btot[b]; if (m > CAP) m = CAP;   // memory-safety clamp (never hits)
    lc[t] = 0;
    __syncthreads();
    for (int i = t; i < m; i += 256) {
        unsigned v = bpack[beg + i];
        ebuf[i] = v;
        atomicAdd(&lc[v >> 24], 1);
    }
    __syncthreads();
    int myc = lc[t];
    sc[t] = myc; __syncthreads();
    for (int off = 1; off < 256; off <<= 1) {
        int v = (t >= off) ? sc[t - off] : 0;
        __syncthreads();
        sc[t] += v;
        __syncthreads();
    }
    int excl = sc[t] - myc;
    int node = b * 256 + t;
    if (node < N) { cnt[node] = myc; rowptr[node] = beg + excl; }
    lc[t] = excl;               // bucket-local cursor
    __syncthreads();
    for (int i = t; i < m; i += 256) {
        unsigned v = ebuf[i];
        int pos = atomicAdd(&lc[v >> 24], 1);
        bpack[beg + pos] = v & 0xFFFFFFu;   // now holds src only (perm)
    }
}

// ---------------------------------------------------------------------------
// Kernel 6: per-destination gather-sum over bf16 x, FUSED mean+noise+bf16.
// 16 lanes per node, 8-deep unrolled (8 rows in flight per lane). Writes
// MFMA-ready bf16 g rows into the first 256B of each 512B fp32 out-row slot.
// ---------------------------------------------------------------------------
__global__ __launch_bounds__(256) void gather_fuse(
    const unsigned short* __restrict__ xh, const unsigned int* __restrict__ perm,
    const int* __restrict__ rowptr, const int* __restrict__ cnt,
    const float* __restrict__ noise, unsigned short* __restrict__ g, int N)
{
    long long t = (long long)blockIdx.x * blockDim.x + threadIdx.x;
    int n = (int)(t >> 4);
    int c = (int)(t & 15);
    if (n >= N) return;
    int beg = rowptr[n];
    int deg = cnt[n];
    float a0 = 0.f, a1 = 0.f, a2 = 0.f, a3 = 0.f, a4 = 0.f, a5 = 0.f, a6 = 0.f, a7 = 0.f;
    const unsigned short* xb = xh + c * 8;   // this lane's 16B column of every row
    int i = 0;
    for (; i + 7 < deg; i += 8) {
        unsigned s0 = perm[beg + i];
        unsigned s1 = perm[beg + i + 1];
        unsigned s2 = perm[beg + i + 2];
        unsigned s3 = perm[beg + i + 3];
        unsigned s4 = perm[beg + i + 4];
        unsigned s5 = perm[beg + i + 5];
        unsigned s6 = perm[beg + i + 6];
        unsigned s7 = perm[beg + i + 7];
        uint4 u0 = *(const uint4*)(xb + (long long)s0 * NHID);
        uint4 u1 = *(const uint4*)(xb + (long long)s1 * NHID);
        uint4 u2 = *(const uint4*)(xb + (long long)s2 * NHID);
        uint4 u3 = *(const uint4*)(xb + (long long)s3 * NHID);
        uint4 u4 = *(const uint4*)(xb + (long long)s4 * NHID);
        uint4 u5 = *(const uint4*)(xb + (long long)s5 * NHID);
        uint4 u6 = *(const uint4*)(xb + (long long)s6 * NHID);
        uint4 u7 = *(const uint4*)(xb + (long long)s7 * NHID);
        a0 += ((bf_lo(u0.x) + bf_lo(u1.x)) + (bf_lo(u2.x) + bf_lo(u3.x)))
            + ((bf_lo(u4.x) + bf_lo(u5.x)) + (bf_lo(u6.x) + bf_lo(u7.x)));
        a1 += ((bf_hi(u0.x) + bf_hi(u1.x)) + (bf_hi(u2.x) + bf_hi(u3.x)))
            + ((bf_hi(u4.x) + bf_hi(u5.x)) + (bf_hi(u6.x) + bf_hi(u7.x)));
        a2 += ((bf_lo(u0.y) + bf_lo(u1.y)) + (bf_lo(u2.y) + bf_lo(u3.y)))
            + ((bf_lo(u4.y) + bf_lo(u5.y)) + (bf_lo(u6.y) + bf_lo(u7.y)));
        a3 += ((bf_hi(u0.y) + bf_hi(u1.y)) + (bf_hi(u2.y) + bf_hi(u3.y)))
            + ((bf_hi(u4.y) + bf_hi(u5.y)) + (bf_hi(u6.y) + bf_hi(u7.y)));
        a4 += ((bf_lo(u0.z) + bf_lo(u1.z)) + (bf_lo(u2.z) + bf_lo(u3.z)))
            + ((bf_lo(u4.z) + bf_lo(u5.z)) + (bf_lo(u6.z) + bf_lo(u7.z)));
        a5 += ((bf_hi(u0.z) + bf_hi(u1.z)) + (bf_hi(u2.z) + bf_hi(u3.z)))
            + ((bf_hi(u4.z) + bf_hi(u5.z)) + (bf_hi(u6.z) + bf_hi(u7.z)));
        a6 += ((bf_lo(u0.w) + bf_lo(u1.w)) + (bf_lo(u2.w) + bf_lo(u3.w)))
            + ((bf_lo(u4.w) + bf_lo(u5.w)) + (bf_lo(u6.w) + bf_lo(u7.w)));
        a7 += ((bf_hi(u0.w) + bf_hi(u1.w)) + (bf_hi(u2.w) + bf_hi(u3.w)))
            + ((bf_hi(u4.w) + bf_hi(u5.w)) + (bf_hi(u6.w) + bf_hi(u7.w)));
    }
    for (; i + 3 < deg; i += 4) {
        unsigned s0 = perm[beg + i];
        unsigned s1 = perm[beg + i + 1];
        unsigned s2 = perm[beg + i + 2];
        unsigned s3 = perm[beg + i + 3];
        uint4 u0 = *(const uint4*)(xb + (long long)s0 * NHID);
        uint4 u1 = *(const uint4*)(xb + (long long)s1 * NHID);
        uint4 u2 = *(const uint4*)(xb + (long long)s2 * NHID);
        uint4 u3 = *(const uint4*)(xb + (long long)s3 * NHID);
        a0 += (bf_lo(u0.x) + bf_lo(u1.x)) + (bf_lo(u2.x) + bf_lo(u3.x));
        a1 += (bf_hi(u0.x) + bf_hi(u1.x)) + (bf_hi(u2.x) + bf_hi(u3.x));
        a2 += (bf_lo(u0.y) + bf_lo(u1.y)) + (bf_lo(u2.y) + bf_lo(u3.y));
        a3 += (bf_hi(u0.y) + bf_hi(u1.y)) + (bf_hi(u2.y) + bf_hi(u3.y));
        a4 += (bf_lo(u0.z) + bf_lo(u1.z)) + (bf_lo(u2.z) + bf_lo(u3.z));
        a5 += (bf_hi(u0.z) + bf_hi(u1.z)) + (bf_hi(u2.z) + bf_hi(u3.z));
        a6 += (bf_lo(u0.w) + bf_lo(u1.w)) + (bf_lo(u2.w) + bf_lo(u3.w));
        a7 += (bf_hi(u0.w) + bf_hi(u1.w)) + (bf_hi(u2.w) + bf_hi(u3.w));
    }
    for (; i < deg; ++i) {
        unsigned s0 = perm[beg + i];
        uint4 u = *(const uint4*)(xb + (long long)s0 * NHID);
        a0 += bf_lo(u.x); a1 += bf_hi(u.x);
        a2 += bf_lo(u.y); a3 += bf_hi(u.y);
        a4 += bf_lo(u.z); a5 += bf_hi(u.z);
        a6 += bf_lo(u.w); a7 += bf_hi(u.w);
    }
    float inv = 1.0f / fmaxf((float)deg, 1.0f);
    const float* nr = noise + (long long)n * NHID + c * 8;
    float4 n0 = *(const float4*)nr;
    float4 n1 = *(const float4*)(nr + 4);
    ushort4 p, q;
    p.x = f2bf_rn(fmaf(a0, inv, n0.x));
    p.y = f2bf_rn(fmaf(a1, inv, n0.y));
    p.z = f2bf_rn(fmaf(a2, inv, n0.z));
    p.w = f2bf_rn(fmaf(a3, inv, n0.w));
    q.x = f2bf_rn(fmaf(a4, inv, n1.x));
    q.y = f2bf_rn(fmaf(a5, inv, n1.y));
    q.z = f2bf_rn(fmaf(a6, inv, n1.z));
    q.w = f2bf_rn(fmaf(a7, inv, n1.w));
    unsigned short* go = g + (long long)n * 256 + c * 8;   // 16B-aligned
    *(ushort4*)go = p;
    *(ushort4*)(go + 4) = q;
}

// ---------------------------------------------------------------------------
// Kernel 7: MFMA MLP. 4 waves/block, 16 nodes/wave (64 nodes/block).
// Reads MFMA-ready bf16 g rows aliased inside `out` (row n's g at byte 512n,
// length 256B), then overwrites out rows in place. Wave-private alias, race-
// free; `out` is NOT __restrict__ so load/store order vs the alias holds.
// ---------------------------------------------------------------------------
__global__ __launch_bounds__(256) void mlp_mfma(
    float* out,                          // in: g (bf16, interleaved), out: x_gen
    const float* __restrict__ W1, const float* __restrict__ b1,
    const float* __restrict__ W2, const float* __restrict__ b2,
    int N)
{
    __shared__ __align__(16) unsigned short w1t[64 * 136];   // W1^T [n][k], pad+8
    __shared__ __align__(16) unsigned short w2t[128 * 72];   // W2^T [n][k], pad+8
    __shared__ __align__(16) unsigned short ht[4][16 * 72];  // per-wave h [m][k], pad+8
    __shared__ float b1s[HDIM];
    __shared__ float b2s[NHID];

    int t = threadIdx.x;
    int wave = t >> 6;
    int lane = t & 63;
    int m = lane & 15;
    int quad = lane >> 4;

    #pragma unroll 4
    for (int p = 0; p < 32; ++p) {               // W1: [128][64] fp32
        int idx = p * 256 + t;
        int k = idx >> 6, n = idx & 63;
        w1t[n * 136 + k] = f2bf_rn(W1[idx]);
    }
    #pragma unroll 4
    for (int p = 0; p < 32; ++p) {               // W2: [64][128] fp32
        int idx = p * 256 + t;
        int k = idx >> 7, n = idx & 127;
        w2t[n * 72 + k] = f2bf_rn(W2[idx]);
    }
    if (t < HDIM) b1s[t] = b1[t];
    else if (t < HDIM + NHID) b2s[t - HDIM] = b2[t - HDIM];
    __syncthreads();

    int node = blockIdx.x * 64 + wave * 16 + m;
    int nodec = node < N ? node : N - 1;         // clamp (N%64==0 normally)

    const unsigned short* grow = (const unsigned short*)out + (long long)nodec * 256;
    bf16x8 afrag[4];
    #pragma unroll
    for (int kc = 0; kc < 4; ++kc)
        afrag[kc] = *(const bf16x8*)(grow + kc * 32 + quad * 8);

    unsigned short* hw = &ht[wave][0];
    #pragma unroll
    for (int nt = 0; nt < 4; ++nt) {
        f32x4 acc = {0.f, 0.f, 0.f, 0.f};
        #pragma unroll
        for (int kc = 0; kc < 4; ++kc) {
            bf16x8 bfrag = *(const bf16x8*)&w1t[(nt * 16 + m) * 136 + kc * 32 + quad * 8];
            acc = __builtin_amdgcn_mfma_f32_16x16x32_bf16(afrag[kc], bfrag, acc, 0, 0, 0);
        }
        float bb = b1s[nt * 16 + m];
        #pragma unroll
        for (int r = 0; r < 4; ++r) {
            // C/D: row = quad*4+r, col = m  (verified m89/m91)
            hw[(quad * 4 + r) * 72 + nt * 16 + m] = f2bf_rn(fmaxf(acc[r] + bb, 0.0f));
        }
    }

    bf16x8 a2[2];
    #pragma unroll
    for (int kc = 0; kc < 2; ++kc)
        a2[kc] = *(const bf16x8*)&hw[m * 72 + kc * 32 + quad * 8];

    float* obase = out + ((long long)blockIdx.x * 64 + wave * 16) * NHID;
    #pragma unroll
    for (int nt = 0; nt < 8; ++nt) {
        f32x4 acc = {0.f, 0.f, 0.f, 0.f};
        #pragma unroll
        for (int kc = 0; kc < 2; ++kc) {
            bf16x8 bfrag = *(const bf16x8*)&w2t[(nt * 16 + m) * 72 + kc * 32 + quad * 8];
            acc = __builtin_amdgcn_mfma_f32_16x16x32_bf16(a2[kc], bfrag, acc, 0, 0, 0);
        }
        float bb = b2s[nt * 16 + m];
        #pragma unroll
        for (int r = 0; r < 4; ++r) {
            int orow = blockIdx.x * 64 + wave * 16 + quad * 4 + r;
            if (orow < N)
                obase[(quad * 4 + r) * NHID + nt * 16 + m] = fmaxf(acc[r] + bb, 0.0f);
        }
    }
}

// ---------------------------------------------------------------------------
extern "C" void kernel_launch(void* const* d_in, const int* in_sizes, int n_in,
                              void* d_out, int out_size, void* d_ws, size_t ws_size,
                              hipStream_t stream) {
    const float* x     = (const float*)d_in[0];
    const int*   ei    = (const int*)d_in[1];
    // d_in[2] = batch (unused by reference computation)
    const float* noise = (const float*)d_in[3];
    const float* W1    = (const float*)d_in[4];
    const float* b1    = (const float*)d_in[5];
    const float* W2    = (const float*)d_in[6];
    const float* b2    = (const float*)d_in[7];
    float* out = (float*)d_out;

    const int N = in_sizes[2];          // 200000
    const int E = in_sizes[1] / 2;      // 3200000
    const int* src = ei;
    const int* dst = ei + E;
    const int NBKT = (N + 255) >> 8;    // 782 buckets of 256 nodes
    const int EB = (int)(((long long)E + EPB - 1) / EPB);   // 391 edge blocks

    // workspace layout:
    // hmat[EB*MAXBKT]  btot[MAXBKT]  bbase[MAXBKT]  cnt[N]  rowptr[N]
    // bpack[E] (packed; aliased as perm)  xh[N*NHID] (bf16)
    int* hmat           = (int*)d_ws;
    int* btot           = hmat + (size_t)EB * MAXBKT;
    int* bbase          = btot + MAXBKT;
    int* cnt            = bbase + MAXBKT;
    int* rowptr         = cnt + N;
    unsigned int* bpack = (unsigned int*)(rowptr + N);
    unsigned short* xh  = (unsigned short*)(bpack + (size_t)E);

    // 1. fused per-block histogram (blocks < EB) + x->bf16 prep (rest)
    long long total8 = (long long)N * NHID / 8;
    int prepB = (int)((total8 + 255) / 256);
    hist_prep<<<EB + prepB, 256, 0, stream>>>(dst, hmat, x, xh, E, EB, total8);
    // 2. per-bucket scan over blocks: counts -> local starts; bucket totals
    scan_blocks<<<NBKT, 256, 0, stream>>>(hmat, btot, EB);
    // 3. bucket totals -> packed bucket bases
    scan_bbase<<<1, 1024, 0, stream>>>(btot, bbase, NBKT);
    // 4. deterministic write-coalesced scatter into packed buckets
    scatter_det<<<EB, 256, 0, stream>>>(src, dst, hmat, bbase, bpack, E, NBKT);
    // 5. in-place per-bucket sort -> perm (=bpack), cnt, rowptr
    bucket_build<<<NBKT, 256, 0, stream>>>(bpack, bbase, btot, cnt, rowptr, N);
    // 6. gather-sum + mean + noise + bf16 pack -> g (aliased into d_out)
    {
        long long total = (long long)N * 16;
        gather_fuse<<<(int)((total + 255) / 256), 256, 0, stream>>>(
            xh, bpack, rowptr, cnt, noise, (unsigned short*)out, N);
    }
    // 7. MFMA MLP in place on d_out (reads aliased bf16 g, writes fp32 x_gen)
    mlp_mfma<<<(N + 63) / 64, 256, 0, stream>>>(out, W1, b1, W2, b2, N);
}